// Round 1
// baseline (274.990 us; speedup 1.0000x reference)
//
#include <hip/hip_runtime.h>

#define L_ 9216

typedef unsigned int uint;
typedef unsigned short ushort;
typedef __attribute__((ext_vector_type(8))) short short8;
typedef __attribute__((ext_vector_type(4))) float f32x4;

#define MFMA16(a, b, c) __builtin_amdgcn_mfma_f32_16x16x32_bf16(a, b, c, 0, 0, 0)

__device__ __forceinline__ ushort f2bf(float f) {
  uint u = __float_as_uint(f);
  return (ushort)((u + 0x7fffu + ((u >> 16) & 1u)) >> 16);
}

// ---------------- projection: Q/K (l2-normalized) and V ----------------
// grid.x = 72 (256 positions each), grid.y = 3 (0=Q, 1=K, 2=V), 128 threads.
__global__ __launch_bounds__(128) void proj_kernel(
    const float* __restrict__ x, const float* __restrict__ x_enc,
    const float* __restrict__ Wq, const float* __restrict__ bq,
    const float* __restrict__ Wk, const float* __restrict__ bk,
    const float* __restrict__ Wv, const float* __restrict__ bv,
    ushort* __restrict__ Qb, ushort* __restrict__ Kb, ushort* __restrict__ Vb) {
  const int task = blockIdx.y;
  const int gp0 = blockIdx.x * 256;
  const int b = gp0 / L_;
  const int p0 = gp0 - b * L_;
  const float* W;
  const float* bias;
  const float* X;
  int CC;
  if (task == 0) { W = Wq; bias = bq; X = x_enc + (size_t)b * 96 * L_; CC = 96; }
  else if (task == 1) { W = Wk; bias = bk; X = x_enc + (size_t)b * 96 * L_; CC = 96; }
  else { W = Wv; bias = bv; X = x + (size_t)b * 64 * L_; CC = 64; }

  __shared__ float Wt[96 * 64];  // W transposed: Wt[c][o]
  for (int i = threadIdx.x; i < CC * 64; i += 128) {
    int o = i / CC, c = i - o * CC;
    Wt[c * 64 + o] = W[i];
  }
  __syncthreads();

  const int t = threadIdx.x;
  const int p1 = p0 + t, p2 = p1 + 128;

  float a0[64], a1[64];
#pragma unroll
  for (int o = 0; o < 64; o++) { a0[o] = 0.f; a1[o] = 0.f; }

  for (int c = 0; c < CC; c++) {
    float xv0 = X[(size_t)c * L_ + p1];
    float xv1 = X[(size_t)c * L_ + p2];
    const float4* wr = (const float4*)&Wt[c * 64];
#pragma unroll
    for (int o4 = 0; o4 < 16; o4++) {
      float4 wv = wr[o4];
      a0[4 * o4 + 0] += wv.x * xv0; a1[4 * o4 + 0] += wv.x * xv1;
      a0[4 * o4 + 1] += wv.y * xv0; a1[4 * o4 + 1] += wv.y * xv1;
      a0[4 * o4 + 2] += wv.z * xv0; a1[4 * o4 + 2] += wv.z * xv1;
      a0[4 * o4 + 3] += wv.w * xv0; a1[4 * o4 + 3] += wv.w * xv1;
    }
  }
#pragma unroll
  for (int o = 0; o < 64; o++) { float bb = bias[o]; a0[o] += bb; a1[o] += bb; }

  if (task < 2) {
    float s0 = 0.f, s1 = 0.f;
#pragma unroll
    for (int o = 0; o < 64; o++) { s0 += a0[o] * a0[o]; s1 += a1[o] * a1[o]; }
    float i0 = 1.0f / fmaxf(sqrtf(s0), 1e-6f);
    float i1 = 1.0f / fmaxf(sqrtf(s1), 1e-6f);
    ushort* dst = (task == 0 ? Qb : Kb);
    uint* d0 = (uint*)(dst + ((size_t)(b * L_ + p1)) * 64);
    uint* d1 = (uint*)(dst + ((size_t)(b * L_ + p2)) * 64);
#pragma unroll
    for (int o2 = 0; o2 < 32; o2++) {
      d0[o2] = (uint)f2bf(a0[2 * o2] * i0) | ((uint)f2bf(a0[2 * o2 + 1] * i0) << 16);
      d1[o2] = (uint)f2bf(a1[2 * o2] * i1) | ((uint)f2bf(a1[2 * o2 + 1] * i1) << 16);
    }
  } else {
#pragma unroll
    for (int o = 0; o < 64; o++) {
      Vb[(size_t)(b * 64 + o) * L_ + p1] = f2bf(a0[o]);
      Vb[(size_t)(b * 64 + o) * L_ + p2] = f2bf(a1[o]);
    }
  }
}

// ---------------- flash attention ----------------
// grid = 288 blocks (B * L/64), 256 threads = 4 waves x 16 q-rows.
// Qb,Kb: [b][pos][64] bf16 (l2-normed). Vb: [b][dv][pos] bf16.
// out: [b][dv][pos] f32.
__global__ __launch_bounds__(256) void attn_kernel(
    const ushort* __restrict__ Qb, const ushort* __restrict__ Kb,
    const ushort* __restrict__ Vb, float* __restrict__ out) {
  __shared__ __align__(16) ushort K_l[64 * 64];      // [kv][d], XOR-swizzled
  __shared__ __align__(16) ushort V_l[64 * 64];      // [dv][kv], XOR-swizzled
  __shared__ __align__(16) ushort P_l[4 * 16 * 64];  // per-wave [q][kv], swizzled

  const int bid = blockIdx.x;
  // XCD-bijective swizzle: 288 % 8 == 0; contiguous chunk of 36 per XCD,
  // so each XCD's K/V working set is a single batch (2.36 MB < 4 MB L2).
  const int logical = (bid & 7) * 36 + (bid >> 3);
  const int b = logical / 144;
  const int q0 = (logical - b * 144) * 64;

  const int t = threadIdx.x;
  const int lane = t & 63;
  const int w = t >> 6;
  const int l15 = lane & 15;
  const int g = lane >> 4;

  const ushort* Kgb = Kb + (size_t)b * L_ * 64;
  const ushort* Vgb = Vb + (size_t)b * 64 * L_;

  // Q fragments for this wave's 16 rows: B-operand layout (q = lane&15, d = g*8+i)
  const ushort* Qrow = Qb + ((size_t)(b * L_ + q0 + w * 16 + l15)) * 64;
  short8 qf0 = *(const short8*)(Qrow + g * 8);
  short8 qf1 = *(const short8*)(Qrow + 32 + g * 8);

  f32x4 o[4];
#pragma unroll
  for (int i = 0; i < 4; i++) o[i] = (f32x4){0.f, 0.f, 0.f, 0.f};
  float m_run = -1e30f, l_run = 0.f;

  for (int kt = 0; kt < 144; ++kt) {
    const int j0 = kt * 64;
    __syncthreads();
    // stage K (rows=kv, cols=d) and V^T (rows=dv, cols=kv), 8KB each.
#pragma unroll
    for (int pp = 0; pp < 2; pp++) {
      int idx = pp * 256 + t;
      int r = idx >> 3;
      int c8 = (idx & 7) << 3;
      *(uint4*)&K_l[(r * 64 + c8) ^ ((r & 7) << 3)] =
          *(const uint4*)(Kgb + (size_t)(j0 + r) * 64 + c8);
      *(uint4*)&V_l[(r * 64 + c8) ^ ((r & 7) << 3)] =
          *(const uint4*)(Vgb + (size_t)r * L_ + j0 + c8);
    }
    __syncthreads();

    // S_sw[kv][q] = K·Q^T: lane holds S for q=l15, kv = k2*16 + g*4 + r
    f32x4 s[4];
#pragma unroll
    for (int k2 = 0; k2 < 4; k2++) {
      int row = k2 * 16 + l15;
      int sw = (row & 7) << 3;
      short8 ak0 = *(const short8*)&K_l[(row * 64 + g * 8) ^ sw];
      short8 ak1 = *(const short8*)&K_l[(row * 64 + 32 + g * 8) ^ sw];
      f32x4 z = {0.f, 0.f, 0.f, 0.f};
      z = MFMA16(ak0, qf0, z);
      z = MFMA16(ak1, qf1, z);
      s[k2] = z;
    }

    // online softmax (per q-row = per l15; 4 lanes per row -> shfl 16,32)
    float mt = -1e30f;
#pragma unroll
    for (int k2 = 0; k2 < 4; k2++)
#pragma unroll
      for (int r = 0; r < 4; r++) mt = fmaxf(mt, s[k2][r]);
    mt = fmaxf(mt, __shfl_xor(mt, 16));
    mt = fmaxf(mt, __shfl_xor(mt, 32));

    float mn = fmaxf(m_run, mt);
    float al = exp2f((m_run - mn) * 1.44269504f);
    float ps = 0.f;
    ushort pb[16];
#pragma unroll
    for (int k2 = 0; k2 < 4; k2++)
#pragma unroll
      for (int r = 0; r < 4; r++) {
        float pv = exp2f((s[k2][r] - mn) * 1.44269504f);
        ps += pv;
        pb[k2 * 4 + r] = f2bf(pv);
      }
    ps += __shfl_xor(ps, 16);
    ps += __shfl_xor(ps, 32);
    l_run = l_run * al + ps;
    m_run = mn;
#pragma unroll
    for (int i = 0; i < 4; i++) o[i] = o[i] * al;

    // write P to per-wave LDS [q][kv] (swizzled on q), read back as B-frag
    const int swp = (l15 & 7) << 3;
#pragma unroll
    for (int k2 = 0; k2 < 4; k2++) {
      uint lo = (uint)pb[k2 * 4 + 0] | ((uint)pb[k2 * 4 + 1] << 16);
      uint hi = (uint)pb[k2 * 4 + 2] | ((uint)pb[k2 * 4 + 3] << 16);
      int e = (l15 * 64 + k2 * 16 + g * 4) ^ swp;
      uint2 v;
      v.x = lo;
      v.y = hi;
      *(uint2*)&P_l[w * 1024 + e] = v;
    }

    short8 bp0 = *(const short8*)&P_l[w * 1024 + ((l15 * 64 + g * 8) ^ swp)];
    short8 bp1 = *(const short8*)&P_l[w * 1024 + ((l15 * 64 + 32 + g * 8) ^ swp)];
    // O^T[dv][q] += V^T · P^T  (A = V^T rows dv, B = P^T cols q)
#pragma unroll
    for (int dt = 0; dt < 4; dt++) {
      int vrow = dt * 16 + l15;
      int swv = (vrow & 7) << 3;
      short8 av0 = *(const short8*)&V_l[(vrow * 64 + g * 8) ^ swv];
      short8 av1 = *(const short8*)&V_l[(vrow * 64 + 32 + g * 8) ^ swv];
      o[dt] = MFMA16(av0, bp0, o[dt]);
      o[dt] = MFMA16(av1, bp1, o[dt]);
    }
  }

  float inv = 1.0f / l_run;
  const int qg = q0 + w * 16 + l15;
#pragma unroll
  for (int dt = 0; dt < 4; dt++)
#pragma unroll
    for (int r = 0; r < 4; r++) {
      int dv = dt * 16 + g * 4 + r;
      out[(size_t)(b * 64 + dv) * L_ + qg] = o[dt][r] * inv;
    }
}

extern "C" void kernel_launch(void* const* d_in, const int* in_sizes, int n_in,
                              void* d_out, int out_size, void* d_ws, size_t ws_size,
                              hipStream_t stream) {
  const float* x = (const float*)d_in[0];
  const float* x_enc = (const float*)d_in[1];
  const float* Wq = (const float*)d_in[2];
  const float* bq = (const float*)d_in[3];
  const float* Wk = (const float*)d_in[4];
  const float* bk = (const float*)d_in[5];
  const float* Wv = (const float*)d_in[6];
  const float* bv = (const float*)d_in[7];
  float* out = (float*)d_out;

  ushort* Qb = (ushort*)d_ws;
  ushort* Kb = Qb + (size_t)2 * L_ * 64;
  ushort* Vb = Kb + (size_t)2 * L_ * 64;

  proj_kernel<<<dim3(72, 3), 128, 0, stream>>>(x, x_enc, Wq, bq, Wk, bk, Wv, bv,
                                               Qb, Kb, Vb);
  attn_kernel<<<288, 256, 0, stream>>>(Qb, Kb, Vb, out);
}

// Round 3
// 123.788 us; speedup vs baseline: 2.2215x; 2.2215x over previous
//
#include <hip/hip_runtime.h>

#define L_ 9216

typedef unsigned int uint;
typedef unsigned short ushort;
typedef __attribute__((ext_vector_type(8))) short short8;
typedef __attribute__((ext_vector_type(4))) float f32x4;
typedef __attribute__((ext_vector_type(16))) float f32x16;
typedef __attribute__((ext_vector_type(4))) unsigned uint4v;

#define MFMA32(a, b, c) __builtin_amdgcn_mfma_f32_32x32x16_bf16(a, b, c, 0, 0, 0)

#if __has_builtin(__builtin_amdgcn_exp2f)
#define EXP2(x) __builtin_amdgcn_exp2f(x)
#else
#define EXP2(x) exp2f(x)
#endif

#define GLOAD_LDS16(g, l)                                            \
  __builtin_amdgcn_global_load_lds(                                  \
      (const __attribute__((address_space(1))) unsigned int*)(g),    \
      (__attribute__((address_space(3))) unsigned int*)(l), 16, 0, 0)

union B8 {
  uint4v u;
  short8 s;
};

__device__ __forceinline__ ushort f2bf(float f) {
  uint u = __float_as_uint(f);
  return (ushort)((u + 0x7fffu + ((u >> 16) & 1u)) >> 16);
}

__device__ __forceinline__ f32x16 zero16() {
  f32x16 v;
#pragma unroll
  for (int i = 0; i < 16; i++) v[i] = 0.f;
  return v;
}

// ---------------- projection: Q/K (l2-normalized) and V ----------------
// grid = (144, 3): 128 positions per block, 1 per thread. task 0=Q,1=K,2=V.
__global__ __launch_bounds__(128) void proj_kernel(
    const float* __restrict__ x, const float* __restrict__ x_enc,
    const float* __restrict__ Wq, const float* __restrict__ bq,
    const float* __restrict__ Wk, const float* __restrict__ bk,
    const float* __restrict__ Wv, const float* __restrict__ bv,
    ushort* __restrict__ Qb, ushort* __restrict__ Kb, ushort* __restrict__ Vb) {
  const int task = blockIdx.y;
  const int gp = blockIdx.x * 128 + threadIdx.x;  // 0..18431
  const int b = (blockIdx.x * 128) / L_;          // block-uniform (128 | 9216)
  const int p = gp - b * L_;

  const float* W;
  const float* bias;
  const float* X;
  int CC;
  if (task == 0) { W = Wq; bias = bq; X = x_enc + (size_t)b * 96 * L_; CC = 96; }
  else if (task == 1) { W = Wk; bias = bk; X = x_enc + (size_t)b * 96 * L_; CC = 96; }
  else { W = Wv; bias = bv; X = x + (size_t)b * 64 * L_; CC = 64; }

  __shared__ float Wt[96 * 64];  // W transposed: Wt[c][o]
  for (int i = threadIdx.x; i < CC * 64; i += 128) {
    int o = i / CC, c = i - o * CC;
    Wt[c * 64 + o] = W[i];
  }
  __syncthreads();

  float a0[64];
#pragma unroll
  for (int o = 0; o < 64; o++) a0[o] = 0.f;

#pragma unroll 4
  for (int c = 0; c < CC; c++) {
    float xv = X[(size_t)c * L_ + p];
    const float4* wr = (const float4*)&Wt[c * 64];
#pragma unroll
    for (int o4 = 0; o4 < 16; o4++) {
      float4 wv = wr[o4];
      a0[4 * o4 + 0] += wv.x * xv;
      a0[4 * o4 + 1] += wv.y * xv;
      a0[4 * o4 + 2] += wv.z * xv;
      a0[4 * o4 + 3] += wv.w * xv;
    }
  }
#pragma unroll
  for (int o = 0; o < 64; o++) a0[o] += bias[o];

  if (task < 2) {
    float s0 = 0.f;
#pragma unroll
    for (int o = 0; o < 64; o++) s0 += a0[o] * a0[o];
    float i0 = 1.0f / fmaxf(sqrtf(s0), 1e-6f);
    ushort* dst = (task == 0 ? Qb : Kb);
    uint* d0 = (uint*)(dst + (size_t)gp * 64);
#pragma unroll
    for (int o2 = 0; o2 < 32; o2++)
      d0[o2] = (uint)f2bf(a0[2 * o2] * i0) | ((uint)f2bf(a0[2 * o2 + 1] * i0) << 16);
  } else {
#pragma unroll
    for (int o = 0; o < 64; o++)
      Vb[(size_t)(b * 64 + o) * L_ + p] = f2bf(a0[o]);
  }
}

// ---------------- flash attention, KV-split ----------------
// grid = 144*SPLIT blocks, 256 thr = 4 waves x 32 q-rows (128 q/block).
// Qb,Kb: [b][pos][64] bf16 (l2-normed). Vb: [b][dv][pos] bf16.
// OP: [split][b][dv][L] fp32 unnormalized. LB: [split][b][L] fp32 denoms.
__global__ __launch_bounds__(256) void attn_kernel(
    const ushort* __restrict__ Qb, const ushort* __restrict__ Kb,
    const ushort* __restrict__ Vb, float* __restrict__ OP,
    float* __restrict__ LB, int tps) {
  __shared__ __align__(16) ushort K_l[2][64 * 64];  // [buf][kv][d], swizzled
  __shared__ __align__(16) ushort V_l[2][64 * 64];  // [buf][dv][kv], swizzled

  const int nwg = gridDim.x;
  const int chunk = nwg >> 3;  // nwg % 8 == 0 always (144*SPLIT)
  const int bid = blockIdx.x;
  const int logical = (bid & 7) * chunk + (bid >> 3);
  const int split = logical / 144;
  const int qidx = logical - split * 144;
  const int b = qidx / 72;
  const int q0 = (qidx - b * 72) * 128;

  const int t = threadIdx.x;
  const int lane = t & 63;
  const int w = t >> 6;
  const int ql = lane & 31;
  const int hs = lane >> 5;

  const ushort* Kg = Kb + (size_t)b * L_ * 64;
  const ushort* Vg = Vb + (size_t)b * 64 * L_;

  // Q fragments: B-operand, col(q) = lane&31, k = hs*8+i per 16-chunk
  const int qrow = q0 + w * 32 + ql;
  const ushort* Qr = Qb + ((size_t)(b * L_ + qrow)) * 64 + hs * 8;
  short8 qf[4];
  qf[0] = *(const short8*)(Qr);
  qf[1] = *(const short8*)(Qr + 16);
  qf[2] = *(const short8*)(Qr + 32);
  qf[3] = *(const short8*)(Qr + 48);

  f32x16 o[2];
  o[0] = zero16();
  o[1] = zero16();
  float ps = 0.f;

  // staging: chunks c0 = t, c1 = t+256 of 512x16B per tile; LDS linear,
  // global source pre-swizzled (inverse of the read-side XOR).
  const int rr = t >> 3, pl = t & 7;
  const int psrc = (pl ^ (rr & 7)) << 3;  // element offset of swizzled source
  const int j0base = split * tps * 64;

#define STAGE(buf, j0)                                                        \
  {                                                                           \
    GLOAD_LDS16(Kg + (size_t)(j0)*64 + rr * 64 + psrc, &K_l[buf][w * 512]);   \
    GLOAD_LDS16(Kg + (size_t)(j0)*64 + (rr + 32) * 64 + psrc,                 \
                &K_l[buf][2048 + w * 512]);                                   \
    GLOAD_LDS16(Vg + (size_t)rr * L_ + (j0) + psrc, &V_l[buf][w * 512]);      \
    GLOAD_LDS16(Vg + (size_t)(rr + 32) * L_ + (j0) + psrc,                    \
                &V_l[buf][2048 + w * 512]);                                   \
  }

  STAGE(0, j0base);

  for (int tt = 0; tt < tps; tt++) {
    __syncthreads();  // drains vmcnt: buf[tt&1] staged; prev compute done
    if (tt + 1 < tps) STAGE((tt + 1) & 1, j0base + (tt + 1) * 64);
    const ushort* Kc = K_l[tt & 1];
    const ushort* Vc = V_l[tt & 1];

    B8 pf[4];
#pragma unroll
    for (int st = 0; st < 2; st++) {
      const int krow = st * 32 + ql;
      const int ksw = (krow & 7) << 3;
      f32x16 sa = zero16();
#pragma unroll
      for (int m = 0; m < 4; m++) {
        short8 kf = *(const short8*)&Kc[(krow * 64 + m * 16 + hs * 8) ^ ksw];
        sa = MFMA32(kf, qf[m], sa);
      }
      // p = exp(s - 1): fixed max (cosine logits <= ~1.004). Truncate to
      // bf16; accumulate denom from truncated values (consistent, unbiased).
      uint Wp[8];
#pragma unroll
      for (int c = 0; c < 4; c++)
#pragma unroll
        for (int rp = 0; rp < 2; rp++) {
          int i0 = 4 * c + 2 * rp;
          float p0 = EXP2(sa[i0] * 1.44269504f - 1.44269504f);
          float p1 = EXP2(sa[i0 + 1] * 1.44269504f - 1.44269504f);
          uint u0 = __float_as_uint(p0) & 0xFFFF0000u;
          uint u1 = __float_as_uint(p1) & 0xFFFF0000u;
          ps += __uint_as_float(u0) + __uint_as_float(u1);
          Wp[2 * c + rp] = u1 | (u0 >> 16);
        }
      // redistribute P across the hs halves: permlane32_swap.
      // swap(A,B): newA[32+i]=oldB[i], newB[i]=oldA[32+i] (dst-hi <-> src-lo).
      // Lane-trace: ra=swap(Wp[4u],Wp[4u+2]) -> ra[0] = fw[0] (hs0: kv(0,1),
      // hs1: kv(8,9)); ra[1] = fw[2] (hs0: kv(4,5), hs1: kv(12,13)).
#pragma unroll
      for (int u = 0; u < 2; u++) {
        auto ra = __builtin_amdgcn_permlane32_swap(Wp[4 * u + 0], Wp[4 * u + 2],
                                                   false, false);
        auto rb = __builtin_amdgcn_permlane32_swap(Wp[4 * u + 1], Wp[4 * u + 3],
                                                   false, false);
        uint4v fw;
        fw[0] = ra[0];
        fw[1] = rb[0];
        fw[2] = ra[1];
        fw[3] = rb[1];
        pf[st * 2 + u].u = fw;
      }
    }

    // O[dv][q] += V^T * P
#pragma unroll
    for (int dt = 0; dt < 2; dt++) {
      const int vrow = dt * 32 + ql;
      const int vsw = (vrow & 7) << 3;
#pragma unroll
      for (int s = 0; s < 4; s++) {
        short8 vf = *(const short8*)&Vc[(vrow * 64 + s * 16 + hs * 8) ^ vsw];
        o[dt] = MFMA32(vf, pf[s].s, o[dt]);
      }
    }
  }

  // epilogue: denom (sum over both hs halves) + unnormalized O
  float pst = ps + __shfl_xor(ps, 32);
  if (hs == 0) LB[(size_t)split * 2 * L_ + (size_t)b * L_ + q0 + w * 32 + ql] = pst;

  float* Ob = OP + (size_t)split * 2 * 64 * L_;
#pragma unroll
  for (int dt = 0; dt < 2; dt++)
#pragma unroll
    for (int r = 0; r < 16; r++) {
      int dv = dt * 32 + (r & 3) + 8 * (r >> 2) + 4 * hs;
      Ob[(size_t)(b * 64 + dv) * L_ + qrow] = o[dt][r];
    }
}

// ---------------- combine splits ----------------
__global__ __launch_bounds__(256) void combine_kernel(
    const float* __restrict__ OP, const float* __restrict__ LB,
    float* __restrict__ out, int nsplit) {
  const size_t e = ((size_t)blockIdx.x * 256 + threadIdx.x) * 4;
  const int b = (int)(e / ((size_t)64 * L_));
  const int q = (int)(e % L_);
  f32x4 os = {0.f, 0.f, 0.f, 0.f};
  f32x4 ls = {0.f, 0.f, 0.f, 0.f};
  for (int s = 0; s < nsplit; s++) {
    os += *(const f32x4*)(OP + (size_t)s * 2 * 64 * L_ + e);
    ls += *(const f32x4*)(LB + (size_t)s * 2 * L_ + (size_t)b * L_ + q);
  }
  f32x4 r;
#pragma unroll
  for (int i = 0; i < 4; i++) r[i] = os[i] / ls[i];
  *(f32x4*)(out + e) = r;
}

extern "C" void kernel_launch(void* const* d_in, const int* in_sizes, int n_in,
                              void* d_out, int out_size, void* d_ws, size_t ws_size,
                              hipStream_t stream) {
  const float* x = (const float*)d_in[0];
  const float* x_enc = (const float*)d_in[1];
  const float* Wq = (const float*)d_in[2];
  const float* bq = (const float*)d_in[3];
  const float* Wk = (const float*)d_in[4];
  const float* bk = (const float*)d_in[5];
  const float* Wv = (const float*)d_in[6];
  const float* bv = (const float*)d_in[7];
  float* out = (float*)d_out;

  ushort* Qb = (ushort*)d_ws;
  ushort* Kb = Qb + (size_t)2 * L_ * 64;
  ushort* Vb = Kb + (size_t)2 * L_ * 64;
  const size_t qkv_bytes = (size_t)3 * 2 * L_ * 64 * 2;          // 7,077,888
  const size_t per_split = ((size_t)2 * 64 * L_ + 2 * L_) * 4;   // 4,792,320

  int SPLIT = 8;
  while (SPLIT > 1 && qkv_bytes + (size_t)SPLIT * per_split > ws_size) SPLIT >>= 1;

  float* OP = (float*)((char*)d_ws + qkv_bytes);
  float* LB = OP + (size_t)SPLIT * 2 * 64 * L_;

  proj_kernel<<<dim3(144, 3), 128, 0, stream>>>(x, x_enc, Wq, bq, Wk, bk, Wv, bv,
                                                Qb, Kb, Vb);
  attn_kernel<<<144 * SPLIT, 256, 0, stream>>>(Qb, Kb, Vb, OP, LB, 144 / SPLIT);
  combine_kernel<<<(2 * 64 * L_ / 4) / 256, 256, 0, stream>>>(OP, LB, out, SPLIT);
}

// Round 4
// 116.517 us; speedup vs baseline: 2.3601x; 1.0624x over previous
//
#include <hip/hip_runtime.h>

#define L_ 9216

typedef unsigned int uint;
typedef unsigned short ushort;
typedef __attribute__((ext_vector_type(8))) short short8;
typedef __attribute__((ext_vector_type(4))) float f32x4;
typedef __attribute__((ext_vector_type(16))) float f32x16;
typedef __attribute__((ext_vector_type(4))) unsigned uint4v;

#define MFMA32(a, b, c) __builtin_amdgcn_mfma_f32_32x32x16_bf16(a, b, c, 0, 0, 0)

#if __has_builtin(__builtin_amdgcn_exp2f)
#define EXP2(x) __builtin_amdgcn_exp2f(x)
#else
#define EXP2(x) exp2f(x)
#endif

#define GLOAD_LDS16(g, l)                                            \
  __builtin_amdgcn_global_load_lds(                                  \
      (const __attribute__((address_space(1))) unsigned int*)(g),    \
      (__attribute__((address_space(3))) unsigned int*)(l), 16, 0, 0)

union B8 {
  uint4v u;
  short8 s;
};

__device__ __forceinline__ ushort f2bf(float f) {
  uint u = __float_as_uint(f);
  return (ushort)((u + 0x7fffu + ((u >> 16) & 1u)) >> 16);
}

__device__ __forceinline__ f32x16 zero16() {
  f32x16 v;
#pragma unroll
  for (int i = 0; i < 16; i++) v[i] = 0.f;
  return v;
}

// ---------------- projection: Q/K (l2-normalized) and V ----------------
// grid = (144, 3), 256 threads: 128 positions/block, 2 threads per position
// (channel halves, pair-reduced via shfl_xor(1) -> DPP). task 0=Q,1=K,2=V.
// Q is pre-scaled by log2e so attn can use exp2 directly.
__global__ __launch_bounds__(256) void proj_kernel(
    const float* __restrict__ x, const float* __restrict__ x_enc,
    const float* __restrict__ Wq, const float* __restrict__ bq,
    const float* __restrict__ Wk, const float* __restrict__ bk,
    const float* __restrict__ Wv, const float* __restrict__ bv,
    ushort* __restrict__ Qb, ushort* __restrict__ Kb, ushort* __restrict__ Vb) {
  const int task = blockIdx.y;
  const int t = threadIdx.x;
  const int half = t & 1;
  const int pidx = t >> 1;  // 0..127
  const int gp = blockIdx.x * 128 + pidx;
  const int b = (blockIdx.x * 128) / L_;  // block-uniform (128 | 9216)
  const int p = gp - b * L_;

  const float* W;
  const float* bias;
  const float* X;
  int CC;
  if (task == 0) { W = Wq; bias = bq; X = x_enc + (size_t)b * 96 * L_; CC = 96; }
  else if (task == 1) { W = Wk; bias = bk; X = x_enc + (size_t)b * 96 * L_; CC = 96; }
  else { W = Wv; bias = bv; X = x + (size_t)b * 64 * L_; CC = 64; }

  __shared__ float Wt[96 * 64];  // W transposed: Wt[c][o]
  for (int i = t; i < CC * 64; i += 256) {
    int o = i / CC, c = i - o * CC;
    Wt[c * 64 + o] = W[i];
  }
  __syncthreads();

  const int ch = CC >> 1;      // channels per half
  const int c0 = half * ch;

  float a0[64];
#pragma unroll
  for (int o = 0; o < 64; o++) a0[o] = 0.f;

#pragma unroll 4
  for (int c = 0; c < ch; c++) {
    float xv = X[(size_t)(c0 + c) * L_ + p];
    const float4* wr = (const float4*)&Wt[(c0 + c) * 64];
#pragma unroll
    for (int o4 = 0; o4 < 16; o4++) {
      float4 wv = wr[o4];
      a0[4 * o4 + 0] += wv.x * xv;
      a0[4 * o4 + 1] += wv.y * xv;
      a0[4 * o4 + 2] += wv.z * xv;
      a0[4 * o4 + 3] += wv.w * xv;
    }
  }
  // pair-reduce across channel halves (lane^1), then bias
#pragma unroll
  for (int o = 0; o < 64; o++) a0[o] += __shfl_xor(a0[o], 1);
#pragma unroll
  for (int o = 0; o < 64; o++) a0[o] += bias[o];

  if (task < 2) {
    float s0 = 0.f;
#pragma unroll
    for (int o = 0; o < 64; o++) s0 += a0[o] * a0[o];
    float i0 = 1.0f / fmaxf(sqrtf(s0), 1e-6f);
    if (task == 0) i0 *= 1.44269504f;  // fold log2e into Q
    ushort* dst = (task == 0 ? Qb : Kb);
    uint* d0 = (uint*)(dst + (size_t)gp * 64);
#pragma unroll
    for (int o2 = 0; o2 < 16; o2++) {
      int oo = half * 16 + o2;
      d0[oo] = (uint)f2bf(a0[2 * oo] * i0) | ((uint)f2bf(a0[2 * oo + 1] * i0) << 16);
    }
  } else {
#pragma unroll
    for (int o = 0; o < 32; o++) {
      int oo = half * 32 + o;
      Vb[(size_t)(b * 64 + oo) * L_ + p] = f2bf(a0[oo]);
    }
  }
}

// ---------------- flash attention, KV-split ----------------
// grid = 144*SPLIT blocks, 256 thr = 4 waves x 32 q-rows (128 q/block).
// Qb (log2e-scaled),Kb: [b][pos][64] bf16. Vb: [b][dv][pos] bf16.
// OP: [split][b][dv][L] fp32 unnormalized. LB: [split][b][L] fp32 denoms.
__global__ __launch_bounds__(256) void attn_kernel(
    const ushort* __restrict__ Qb, const ushort* __restrict__ Kb,
    const ushort* __restrict__ Vb, float* __restrict__ OP,
    float* __restrict__ LB, int tps) {
  __shared__ __align__(16) ushort K_l[2][64 * 64];  // [buf][kv][d], swizzled
  __shared__ __align__(16) ushort V_l[2][64 * 64];  // [buf][dv][kv], swizzled

  const int nwg = gridDim.x;
  const int chunk = nwg >> 3;  // nwg % 8 == 0 always (144*SPLIT)
  const int bid = blockIdx.x;
  const int logical = (bid & 7) * chunk + (bid >> 3);
  const int split = logical / 144;
  const int qidx = logical - split * 144;
  const int b = qidx / 72;
  const int q0 = (qidx - b * 72) * 128;

  const int t = threadIdx.x;
  const int lane = t & 63;
  const int w = t >> 6;
  const int ql = lane & 31;
  const int hs = lane >> 5;

  const ushort* Kg = Kb + (size_t)b * L_ * 64;
  const ushort* Vg = Vb + (size_t)b * 64 * L_;

  // Q fragments: B-operand, col(q) = lane&31, k = hs*8+i per 16-chunk
  const int qrow = q0 + w * 32 + ql;
  const ushort* Qr = Qb + ((size_t)(b * L_ + qrow)) * 64 + hs * 8;
  short8 qf[4];
  qf[0] = *(const short8*)(Qr);
  qf[1] = *(const short8*)(Qr + 16);
  qf[2] = *(const short8*)(Qr + 32);
  qf[3] = *(const short8*)(Qr + 48);

  // ones A-fragment (bf16 1.0) for the denominator MFMA
  B8 onesu;
  onesu.u[0] = 0x3F803F80u;
  onesu.u[1] = 0x3F803F80u;
  onesu.u[2] = 0x3F803F80u;
  onesu.u[3] = 0x3F803F80u;

  f32x16 o[2];
  o[0] = zero16();
  o[1] = zero16();
  f32x16 od = zero16();  // denominator accumulator (all rows identical)

  // staging: LDS linear, global source pre-swizzled (inverse of read XOR).
  const int rr = t >> 3, pl = t & 7;
  const int psrc = (pl ^ (rr & 7)) << 3;
  const int j0base = split * tps * 64;

#define STAGE(buf, j0)                                                        \
  {                                                                           \
    GLOAD_LDS16(Kg + (size_t)(j0)*64 + rr * 64 + psrc, &K_l[buf][w * 512]);   \
    GLOAD_LDS16(Kg + (size_t)(j0)*64 + (rr + 32) * 64 + psrc,                 \
                &K_l[buf][2048 + w * 512]);                                   \
    GLOAD_LDS16(Vg + (size_t)rr * L_ + (j0) + psrc, &V_l[buf][w * 512]);      \
    GLOAD_LDS16(Vg + (size_t)(rr + 32) * L_ + (j0) + psrc,                    \
                &V_l[buf][2048 + w * 512]);                                   \
  }

  STAGE(0, j0base);

  for (int tt = 0; tt < tps; tt++) {
    __syncthreads();  // buf[tt&1] staged; prev compute done
    if (tt + 1 < tps) STAGE((tt + 1) & 1, j0base + (tt + 1) * 64);
    const ushort* Kc = K_l[tt & 1];
    const ushort* Vc = V_l[tt & 1];

    B8 pf[4];
#pragma unroll
    for (int st = 0; st < 2; st++) {
      const int krow = st * 32 + ql;
      const int ksw = (krow & 7) << 3;
      f32x16 sa = zero16();
#pragma unroll
      for (int m = 0; m < 4; m++) {
        short8 kf = *(const short8*)&Kc[(krow * 64 + m * 16 + hs * 8) ^ ksw];
        sa = MFMA32(kf, qf[m], sa);
      }
      // Q pre-scaled by log2e -> p = exp2(sa) = e^s (fixed-max softmax; the
      // missing e^-1 scale cancels between numerator and denominator).
      // Truncate to bf16 and pack two at a time with one v_perm_b32.
      uint Wp[8];
#pragma unroll
      for (int c = 0; c < 4; c++)
#pragma unroll
        for (int rp = 0; rp < 2; rp++) {
          int i0 = 4 * c + 2 * rp;
          float p0 = EXP2(sa[i0]);
          float p1 = EXP2(sa[i0 + 1]);
          Wp[2 * c + rp] = __builtin_amdgcn_perm(
              __float_as_uint(p1), __float_as_uint(p0), 0x07060302u);
        }
      // redistribute P across the hs halves: permlane32_swap
      // (dst-hi <-> src-lo): ra=swap(Wp[4u],Wp[4u+2]) -> fw[0]=ra[0],
      // fw[2]=ra[1].
#pragma unroll
      for (int u = 0; u < 2; u++) {
        auto ra = __builtin_amdgcn_permlane32_swap(Wp[4 * u + 0], Wp[4 * u + 2],
                                                   false, false);
        auto rb = __builtin_amdgcn_permlane32_swap(Wp[4 * u + 1], Wp[4 * u + 3],
                                                   false, false);
        uint4v fw;
        fw[0] = ra[0];
        fw[1] = rb[0];
        fw[2] = ra[1];
        fw[3] = rb[1];
        pf[st * 2 + u].u = fw;
      }
    }

    // denominator: od[*][q] += sum_kv P[kv][q] via ones-row MFMA (same
    // truncated bf16 P the PV consumes -> exactly consistent)
#pragma unroll
    for (int s = 0; s < 4; s++) od = MFMA32(onesu.s, pf[s].s, od);

    // O[dv][q] += V^T * P
#pragma unroll
    for (int dt = 0; dt < 2; dt++) {
      const int vrow = dt * 32 + ql;
      const int vsw = (vrow & 7) << 3;
#pragma unroll
      for (int s = 0; s < 4; s++) {
        short8 vf = *(const short8*)&Vc[(vrow * 64 + s * 16 + hs * 8) ^ vsw];
        o[dt] = MFMA32(vf, pf[s].s, o[dt]);
      }
    }
  }

  // epilogue: denom = od[0] (all rows identical; row 0 lives in hs==0's r=0)
  if (hs == 0) LB[(size_t)split * 2 * L_ + (size_t)b * L_ + qrow] = od[0];

  float* Ob = OP + (size_t)split * 2 * 64 * L_;
#pragma unroll
  for (int dt = 0; dt < 2; dt++)
#pragma unroll
    for (int r = 0; r < 16; r++) {
      int dv = dt * 32 + (r & 3) + 8 * (r >> 2) + 4 * hs;
      Ob[(size_t)(b * 64 + dv) * L_ + qrow] = o[dt][r];
    }
}

// ---------------- combine splits ----------------
__global__ __launch_bounds__(256) void combine_kernel(
    const float* __restrict__ OP, const float* __restrict__ LB,
    float* __restrict__ out, int nsplit) {
  const size_t e = ((size_t)blockIdx.x * 256 + threadIdx.x) * 4;
  const int b = (int)(e / ((size_t)64 * L_));
  const int q = (int)(e % L_);
  f32x4 os = {0.f, 0.f, 0.f, 0.f};
  f32x4 ls = {0.f, 0.f, 0.f, 0.f};
  for (int s = 0; s < nsplit; s++) {
    os += *(const f32x4*)(OP + (size_t)s * 2 * 64 * L_ + e);
    ls += *(const f32x4*)(LB + (size_t)s * 2 * L_ + (size_t)b * L_ + q);
  }
  f32x4 r;
#pragma unroll
  for (int i = 0; i < 4; i++) r[i] = os[i] / ls[i];
  *(f32x4*)(out + e) = r;
}

extern "C" void kernel_launch(void* const* d_in, const int* in_sizes, int n_in,
                              void* d_out, int out_size, void* d_ws, size_t ws_size,
                              hipStream_t stream) {
  const float* x = (const float*)d_in[0];
  const float* x_enc = (const float*)d_in[1];
  const float* Wq = (const float*)d_in[2];
  const float* bq = (const float*)d_in[3];
  const float* Wk = (const float*)d_in[4];
  const float* bk = (const float*)d_in[5];
  const float* Wv = (const float*)d_in[6];
  const float* bv = (const float*)d_in[7];
  float* out = (float*)d_out;

  ushort* Qb = (ushort*)d_ws;
  ushort* Kb = Qb + (size_t)2 * L_ * 64;
  ushort* Vb = Kb + (size_t)2 * L_ * 64;
  const size_t qkv_bytes = (size_t)3 * 2 * L_ * 64 * 2;          // 7,077,888
  const size_t per_split = ((size_t)2 * 64 * L_ + 2 * L_) * 4;   // 4,792,320

  int SPLIT = 8;
  while (SPLIT > 1 && qkv_bytes + (size_t)SPLIT * per_split > ws_size) SPLIT >>= 1;

  float* OP = (float*)((char*)d_ws + qkv_bytes);
  float* LB = OP + (size_t)SPLIT * 2 * 64 * L_;

  proj_kernel<<<dim3(144, 3), 256, 0, stream>>>(x, x_enc, Wq, bq, Wk, bk, Wv, bv,
                                                Qb, Kb, Vb);
  attn_kernel<<<144 * SPLIT, 256, 0, stream>>>(Qb, Kb, Vb, OP, LB, 144 / SPLIT);
  combine_kernel<<<(2 * 64 * L_ / 4) / 256, 256, 0, stream>>>(OP, LB, out, SPLIT);
}